// Round 8
// baseline (185.620 us; speedup 1.0000x reference)
//
#include <hip/hip_runtime.h>
#include <hip/hip_bf16.h>

// ---------------------------------------------------------------------------
// GlobalIntrinsicLinear: Fastfood update + GEMM
//   LL = 1<<20, DD = 1024*768, OUT=1024, IN=768, M = 8*2048 = 16384
// Inputs: x(8,2048,768) f32, theta(2048) f32, W_0(1024,768) f32, b(1024) f32,
//         BB(LL) f32, GG(LL) f32, Pi(LL) int32 (harness narrows int64)
// Output: (8,2048,1024) f32
//
// R8: x fed to GEMM as f32 directly; f32->bf16 pack happens in k7's VALU
//     shadow (k7 is latency-bound with ~80% idle VALU per R7 counters).
//     Deletes k3's 75 MB cast pass + XB buffer entirely. A-tile LDS is f32
//     (32 KB, XOR swizzle at 16-slot granularity); B stays bf16 from k4.
// ---------------------------------------------------------------------------

#define LL (1 << 20)
#define DD (1024 * 768)
#define OUTF 1024
#define INF 768
#define MROWS 16384

typedef __attribute__((ext_vector_type(8))) short s16x8;
typedef __attribute__((ext_vector_type(4))) float f32x4;
typedef __attribute__((ext_vector_type(16))) float f32x16;

__device__ __forceinline__ unsigned short f2bf(float f) {
    union { float f; unsigned u; } v; v.f = f;
    unsigned r = v.u + 0x7FFF + ((v.u >> 16) & 1);   // RNE
    return (unsigned short)(r >> 16);
}

// pack two f32 into bf16x2 (round-half-up; error bounded by 1 ulp, well
// inside the 0.1875 absmax budget)
__device__ __forceinline__ unsigned pkbf(float lo, float hi) {
    union { float f; unsigned u; } a, b;
    a.f = lo; b.f = hi;
    return ((a.u + 0x8000u) >> 16) | ((b.u + 0x8000u) & 0xFFFF0000u);
}

// ---------------------------------------------------------------------------
// K3: fused {FWHT-1024 of the two nonzero rows of BB*theta_pad} + gather +
// FWHT-1024 along low-10 bits + sum(GG^2) block partials.
// One hi-row per block (1024 blocks).
// Math: FWHT_{2^20} of a vector nonzero only at q<2048 collapses to
//   v1[p] = r0[p&1023] + (-1)^{bit10(p)} * r1[p&1023],  r0/r1 = FWHT_1024 rows.
// ---------------------------------------------------------------------------
__global__ void k3_gather_fwht_lo(const int* __restrict__ Pi, const float* __restrict__ GG,
                                  const float* __restrict__ BB, const float* __restrict__ theta,
                                  float* __restrict__ T, float* __restrict__ partial) {
    __shared__ float s[1024];
    __shared__ float r01s[2048];
    __shared__ float ws4[4];
    const int tid = threadIdx.x;
    const int row = blockIdx.x;
    // gather operands early (latency hidden behind r01 butterflies)
    const int4   pv = ((const int4*)Pi)[row * 256 + tid];
    const float4 gv = ((const float4*)GG)[row * 256 + tid];
    for (int j = tid; j < 2048; j += 256) r01s[j] = BB[j] * theta[j];
    for (int h = 1; h < 1024; h <<= 1) {
        __syncthreads();
        for (int w = tid; w < 1024; w += 256) {
            int rr = w >> 9;
            int b  = w & 511;
            int bh = b & (h - 1);
            int i  = ((b - bh) << 1) + bh + rr * 1024;
            float a = r01s[i], c = r01s[i + h];
            r01s[i] = a + c; r01s[i + h] = a - c;
        }
    }
    float g2 = gv.x * gv.x + gv.y * gv.y + gv.z * gv.z + gv.w * gv.w;
    #pragma unroll
    for (int o = 32; o > 0; o >>= 1) g2 += __shfl_down(g2, o, 64);
    if ((tid & 63) == 0) ws4[tid >> 6] = g2;
    __syncthreads();
    {
        int p; float g, v;
        p = pv.x; g = gv.x;
        v = (r01s[p & 1023] + (((p >> 10) & 1) ? -1.0f : 1.0f) * r01s[1024 + (p & 1023)]) * g;
        s[tid * 4 + 0] = v;
        p = pv.y; g = gv.y;
        v = (r01s[p & 1023] + (((p >> 10) & 1) ? -1.0f : 1.0f) * r01s[1024 + (p & 1023)]) * g;
        s[tid * 4 + 1] = v;
        p = pv.z; g = gv.z;
        v = (r01s[p & 1023] + (((p >> 10) & 1) ? -1.0f : 1.0f) * r01s[1024 + (p & 1023)]) * g;
        s[tid * 4 + 2] = v;
        p = pv.w; g = gv.w;
        v = (r01s[p & 1023] + (((p >> 10) & 1) ? -1.0f : 1.0f) * r01s[1024 + (p & 1023)]) * g;
        s[tid * 4 + 3] = v;
    }
    for (int h = 1; h < 1024; h <<= 1) {
        __syncthreads();
        for (int w = tid; w < 512; w += 256) {
            int bh = w & (h - 1);
            int i  = ((w - bh) << 1) + bh;
            float a = s[i], c = s[i + h];
            s[i] = a + c; s[i + h] = a - c;
        }
    }
    __syncthreads();
    float4 v;
    v.x = s[tid * 4 + 0]; v.y = s[tid * 4 + 1]; v.z = s[tid * 4 + 2]; v.w = s[tid * 4 + 3];
    ((float4*)T)[row * 256 + tid] = v;
    if (tid == 0) partial[row] = ws4[0] + ws4[1] + ws4[2] + ws4[3];
}

// ---------------------------------------------------------------------------
// K4: FWHT-1024 along the high-10 bits + W_eff epilogue.
// 128 blocks x 8 lo-columns each; LDS tile [8][1025] (pad -> conflict-free).
// Every block redundantly reduces the 1024 GG^2 partials (4 KB; no global S).
// Epilogue: WB[d] = bf16(W0[d] + v[d]*rsqrt(S*DD)) for d = hi*1024+lo < DD.
// ---------------------------------------------------------------------------
__global__ void k4_fwht_hi(const float* __restrict__ T, const float* __restrict__ partial,
                           const float* __restrict__ W0, ushort* __restrict__ WB) {
    __shared__ float s[8 * 1025];
    __shared__ float rw[5];
    const int tid = threadIdx.x;
    float p = partial[tid] + partial[tid + 256] + partial[tid + 512] + partial[tid + 768];
    #pragma unroll
    for (int o = 32; o > 0; o >>= 1) p += __shfl_down(p, o, 64);
    if ((tid & 63) == 0) rw[tid >> 6] = p;

    const int lo0 = blockIdx.x * 8;
    const float4* T4 = (const float4*)T;
    const int hio = tid >> 1;     // 0..127
    const int q   = tid & 1;      // which float4 of the 8 columns
    for (int hb = 0; hb < 8; hb++) {
        int hi = hb * 128 + hio;
        float4 v = T4[hi * 256 + (lo0 >> 2) + q];
        s[(4 * q + 0) * 1025 + hi] = v.x;
        s[(4 * q + 1) * 1025 + hi] = v.y;
        s[(4 * q + 2) * 1025 + hi] = v.z;
        s[(4 * q + 3) * 1025 + hi] = v.w;
    }
    __syncthreads();
    if (tid == 0) rw[4] = rw[0] + rw[1] + rw[2] + rw[3];
    for (int h = 1; h < 1024; h <<= 1) {
        for (int w = tid; w < 8 * 512; w += 256) {
            int col = w >> 9;
            int b   = w & 511;
            int bh  = b & (h - 1);
            int i   = ((b - bh) << 1) + bh;
            float* pp = s + col * 1025;
            float a = pp[i], c = pp[i + h];
            pp[i] = a + c; pp[i + h] = a - c;
        }
        __syncthreads();
    }
    const float scale = rsqrtf(rw[4] * (float)DD);
    for (int hb = 0; hb < 6; hb++) {
        int hi = hb * 128 + hio;
        int d  = hi * 1024 + lo0 + 4 * q;
        float4 w = *(const float4*)&W0[d];
        ushort4 o;
        o.x = f2bf(w.x + s[(4 * q + 0) * 1025 + hi] * scale);
        o.y = f2bf(w.y + s[(4 * q + 1) * 1025 + hi] * scale);
        o.z = f2bf(w.z + s[(4 * q + 2) * 1025 + hi] * scale);
        o.w = f2bf(w.w + s[(4 * q + 3) * 1025 + hi] * scale);
        *(ushort4*)&WB[d] = o;
    }
}

// ---------------------------------------------------------------------------
// K7: GEMM  C[m][n] = sum_k A[m][k]*B[n][k] + bias[n]
// A: MROWS x 768 f32 (= x, no pre-cast), B: 1024 x 768 bf16 (W_eff), C: f32.
// 128x128 tile, BK=64, 4 waves (2x2), each wave 2x2 MFMA 32x32x16 x4 k-steps.
// A staged as f32 (32 KB LDS), converted to bf16 in-register post-ds_read
// (round-half-up pack, rides the idle VALU). B staged bf16 (16 KB).
// XOR swizzles: A 16B slot s <-> (row=s>>4, c4=(s&15)^(row&15));
//               B 16B slot s <-> (row=s>>3, kc=(s&7)^(row&7)).
// Staging is 256B(A)/128B(B) row-contiguous per lane-group; frag reads hit
// each bank quad <=2x per 16-lane phase.
// Grid x = m-tile: all 8 n-blocks of an A-stripe land on one XCD (id m0%8).
// ---------------------------------------------------------------------------
#define BM 128
#define BN 128
#define BK 64

__global__ __launch_bounds__(256)
void k7_gemm(const float* __restrict__ A, const ushort* __restrict__ B,
             const float* __restrict__ bias, float* __restrict__ C) {
    __shared__ float  AsF[BM * BK];   // 32 KB
    __shared__ ushort Bs [BN * BK];   // 16 KB
    const int tid  = threadIdx.x;
    const int lane = tid & 63;
    const int wave = tid >> 6;
    const int m0 = blockIdx.x * BM;
    const int n0 = blockIdx.y * BN;
    const int wm = (wave & 1) * 64;
    const int wn = (wave >> 1) * 64;

    const int fr_row = lane & 31;     // row within 32-tile
    const int fr_kh  = lane >> 5;     // k-half 0..1 (8 k each)

    f32x16 acc[2][2];
    #pragma unroll
    for (int i = 0; i < 2; i++)
        #pragma unroll
        for (int j = 0; j < 2; j++) acc[i][j] = (f32x16)(0.0f);

    for (int kt = 0; kt < INF; kt += BK) {
        // --- stage A (f32, 2048 slots) ---
        #pragma unroll
        for (int i = 0; i < 8; i++) {
            const int s   = i * 256 + tid;
            const int row = s >> 4;
            const int c4  = (s & 15) ^ (row & 15);
            const float* ga = A + (size_t)(m0 + row) * INF + kt + c4 * 4;
            __builtin_amdgcn_global_load_lds(
                (const __attribute__((address_space(1))) void*)ga,
                (__attribute__((address_space(3))) void*)&AsF[(i * 256 + wave * 64) * 4], 16, 0, 0);
        }
        // --- stage B (bf16, 1024 slots) ---
        #pragma unroll
        for (int i = 0; i < 4; i++) {
            const int s   = i * 256 + tid;
            const int row = s >> 3;
            const int kc  = (s & 7) ^ (row & 7);
            const ushort* gb = B + (size_t)(n0 + row) * INF + kt + kc * 8;
            __builtin_amdgcn_global_load_lds(
                (const __attribute__((address_space(1))) void*)gb,
                (__attribute__((address_space(3))) void*)&Bs[i * 2048 + wave * 512], 16, 0, 0);
        }
        __syncthreads();

        // --- fragments + MFMA, four 16-k steps ---
        #pragma unroll
        for (int ks = 0; ks < 4; ks++) {
            s16x8 af[2], bf[2];
            #pragma unroll
            for (int mi = 0; mi < 2; mi++) {
                const int r  = wm + mi * 32 + fr_row;
                const int c0 = ks * 4 + fr_kh * 2;
                f32x4 a0 = *(const f32x4*)&AsF[(r * 16 + ((c0 + 0) ^ (r & 15))) * 4];
                f32x4 a1 = *(const f32x4*)&AsF[(r * 16 + ((c0 + 1) ^ (r & 15))) * 4];
                union { uint4 u; s16x8 v; } cvt;
                cvt.u.x = pkbf(a0[0], a0[1]);
                cvt.u.y = pkbf(a0[2], a0[3]);
                cvt.u.z = pkbf(a1[0], a1[1]);
                cvt.u.w = pkbf(a1[2], a1[3]);
                af[mi] = cvt.v;
            }
            #pragma unroll
            for (int ni = 0; ni < 2; ni++) {
                const int r  = wn + ni * 32 + fr_row;
                const int kc = ks * 2 + fr_kh;
                bf[ni] = *(const s16x8*)&Bs[(r * 8 + (kc ^ (r & 7))) * 8];
            }
            #pragma unroll
            for (int mi = 0; mi < 2; mi++)
                #pragma unroll
                for (int ni = 0; ni < 2; ni++)
                    acc[mi][ni] = __builtin_amdgcn_mfma_f32_32x32x16_bf16(
                        af[mi], bf[ni], acc[mi][ni], 0, 0, 0);
        }
        __syncthreads();
    }

    // --- epilogue: C/D col=lane&31, row=(reg&3)+8*(reg>>2)+4*(lane>>5) ---
    const int ccol = lane & 31;
    const int rbase = (lane >> 5) * 4;
    #pragma unroll
    for (int ni = 0; ni < 2; ni++) {
        const int n = n0 + wn + ni * 32 + ccol;
        const float bv = bias[n];
        #pragma unroll
        for (int mi = 0; mi < 2; mi++) {
            const int mb = m0 + wm + mi * 32 + rbase;
            #pragma unroll
            for (int r = 0; r < 16; r++) {
                const int m = mb + (r & 3) + 8 * (r >> 2);
                C[(size_t)m * OUTF + n] = acc[mi][ni][r] + bv;
            }
        }
    }
}

// ---------------------------------------------------------------------------
extern "C" void kernel_launch(void* const* d_in, const int* in_sizes, int n_in,
                              void* d_out, int out_size, void* d_ws, size_t ws_size,
                              hipStream_t stream) {
    (void)in_sizes; (void)n_in; (void)out_size; (void)ws_size;
    const float* x     = (const float*)d_in[0];
    const float* theta = (const float*)d_in[1];
    const float* W0    = (const float*)d_in[2];
    const float* bias  = (const float*)d_in[3];
    const float* BB    = (const float*)d_in[4];
    const float* GG    = (const float*)d_in[5];
    const int*   Pi    = (const int*)d_in[6];      // int64 inputs arrive as int32
    float* out = (float*)d_out;

    char* ws = (char*)d_ws;
    float*  T    = (float*)ws;                       // LL f32 = 4194304 B
    ushort* WB   = (ushort*)(ws + 4194304);          // 1024*768 bf16 = 1572864 B
    float*  PART = (float*)(ws + 5767168);           // 1024 f32 partials

    k3_gather_fwht_lo<<<1024, 256, 0, stream>>>(Pi, GG, BB, theta, T, PART);
    k4_fwht_hi<<<128, 256, 0, stream>>>(T, PART, W0, WB);
    k7_gemm  <<<dim3(MROWS/BM, OUTF/BN), 256, 0, stream>>>(x, WB, bias, out);
}